// Round 1
// 932.207 us; speedup vs baseline: 1.4237x; 1.4237x over previous
//
#include <hip/hip_runtime.h>

// Round 6: algebraic restructure. The E x 128 x 128 edge GEMM + m-materialization
// is replaced using:
//   score_e = <hW1[src], h[dst]> + <efeat_e, hT1[dst]> + hb1[dst]
//   sum_e w_e m_e = sum(w hW1[src]) + (sum(w efeat)) @ W1 + (sum w) b1
// Per layer: gemm_n4 (hW1, hT1=h@W1^T, y2, y3, hb1) -> edge_agg (flash-style
// online softmax per node over CSR lists; streams efeat once, gathers
// L3-resident hW1[src]; fp32 register accumulation) -> gemm_fin
// (X@W1 + y2 + b1 + P, leaky, deg0 -> y3).

typedef unsigned short u16;
typedef short bf16x8 __attribute__((ext_vector_type(8)));
typedef float f32x4 __attribute__((ext_vector_type(4)));

#define NEG_SLOPE 0.22916666666666666f

__device__ inline float bf2f(u16 h) { return __uint_as_float(((unsigned)h) << 16); }
__device__ inline u16 f2bf(float f) {
  unsigned u = __float_as_uint(f);
  u += 0x7fffu + ((u >> 16) & 1u);   // RNE
  return (u16)(u >> 16);
}

// ---------------------------------------------------------------------------
// Weight pre-split into MFMA-fragment-major bf16 hi/lo (B-frag for 16x16x32).
// Blocks 0..5: W1_l0, W2_l0, W3_l0, W1_l1, W2_l1, W3_l1. Blocks 6,7: W1^T l0/l1.
// ---------------------------------------------------------------------------
__global__ __launch_bounds__(256)
void prep_weights(const float* w0, const float* w1, const float* w2,
                  const float* w3, const float* w4, const float* w5,
                  const float* c0, const float* c1, const float* c2,
                  const float* c3, const float* c4, const float* c5,
                  u16* __restrict__ wf, float* __restrict__ bf) {
  int b = blockIdx.x, tid = threadIdx.x;
  const float* Ws[8] = {w0, w1, w2, w3, w4, w5, w0, w3};
  const float* Cs[6] = {c0, c1, c2, c3, c4, c5};
  const float* W = Ws[b];
  const bool tr = (b >= 6);
  u16* out = wf + (size_t)b * 32768;
  for (int q = 0; q < 64; ++q) {
    int fi = tid * 64 + q;
    int t = fi >> 11, kc = (fi >> 9) & 3, lane = (fi >> 3) & 63, j = fi & 7;
    int k = kc * 32 + (lane >> 4) * 8 + j;
    int n = t * 16 + (lane & 15);
    float w = tr ? W[n * 128 + k] : W[k * 128 + n];
    u16 hi = f2bf(w);
    u16 lo = f2bf(w - bf2f(hi));
    int base = ((t * 4 + kc) * 2) * 512 + lane * 8 + j;
    out[base] = hi;
    out[base + 512] = lo;
  }
  if (b < 6 && tid < 128) bf[b * 128 + tid] = Cs[b][tid];
}

// ---------------------------------------------------------------------------
// CSR build: hist -> 3-step exclusive scan -> scatter (edge-id + src in CSR order).
// ---------------------------------------------------------------------------
__global__ __launch_bounds__(256)
void hist_k(const int* __restrict__ dst, int* __restrict__ deg, int E) {
  int i = blockIdx.x * 256 + threadIdx.x;
  int stride = gridDim.x * 256;
  for (; i < E; i += stride) atomicAdd(&deg[dst[i]], 1);
}

__global__ __launch_bounds__(256)
void scan1(const int* __restrict__ deg, int* __restrict__ off,
           int* __restrict__ bsum, int N) {
  __shared__ int sh[256];
  int b = blockIdx.x, t = threadIdx.x;
  int base = b * 1024 + t * 4;
  int v[4];
  #pragma unroll
  for (int i = 0; i < 4; ++i) v[i] = (base + i < N) ? deg[base + i] : 0;
  int s = v[0] + v[1] + v[2] + v[3];
  sh[t] = s;
  __syncthreads();
  for (int o = 1; o < 256; o <<= 1) {
    int x = (t >= o) ? sh[t - o] : 0;
    __syncthreads();
    sh[t] += x;
    __syncthreads();
  }
  int run = sh[t] - s;
  #pragma unroll
  for (int i = 0; i < 4; ++i) {
    if (base + i < N) off[base + i] = run;
    run += v[i];
  }
  if (t == 255) bsum[b] = sh[255];
}

__global__ void scan2(int* __restrict__ bsum, int nb) {
  __shared__ int sh[256];
  int t = threadIdx.x;
  int v = (t < nb) ? bsum[t] : 0;
  sh[t] = v;
  __syncthreads();
  for (int o = 1; o < 256; o <<= 1) {
    int x = (t >= o) ? sh[t - o] : 0;
    __syncthreads();
    sh[t] += x;
    __syncthreads();
  }
  if (t < nb) bsum[t] = sh[t] - v;
}

__global__ __launch_bounds__(256)
void scan3(int* __restrict__ off, const int* __restrict__ bsum,
           int* __restrict__ cursor, int N, int E) {
  int i = blockIdx.x * 256 + threadIdx.x;
  if (i < N) {
    int v = off[i] + bsum[i >> 10];
    off[i] = v;
    cursor[i] = v;
  } else if (i == N) {
    off[N] = E;
  }
}

__global__ __launch_bounds__(256)
void scatter_k(const int* __restrict__ dst, const int* __restrict__ src,
               int* __restrict__ cursor, int* __restrict__ eidx,
               int* __restrict__ csrc, int E) {
  int i = blockIdx.x * 256 + threadIdx.x;
  int stride = gridDim.x * 256;
  for (; i < E; i += stride) {
    int p = atomicAdd(&cursor[dst[i]], 1);
    eidx[p] = i;
    csrc[p] = src[i];
  }
}

// ---------------------------------------------------------------------------
// Fused node GEMMs: stage h once, apply 4 weight sets -> hW1, hT1, y2, y3.
// Epilogue also computes hb1[n] = dot(h[n], b1).
// ---------------------------------------------------------------------------
__global__ __launch_bounds__(256)
void gemm_n4(const float* __restrict__ A,
             const u16* __restrict__ wf1, const u16* __restrict__ wfT,
             const u16* __restrict__ wf2, const u16* __restrict__ wf3,
             const float* __restrict__ biases,
             float* __restrict__ C0, float* __restrict__ C1,
             float* __restrict__ C2, float* __restrict__ C3,
             float* __restrict__ hb1, int M) {
  __shared__ u16 ah[64 * 136];
  __shared__ u16 al[64 * 136];
  const int tid = threadIdx.x;
  const long long rowBase = (long long)blockIdx.x * 64;
  #pragma unroll
  for (int it = 0; it < 8; ++it) {
    int idx = it * 256 + tid;
    int row = idx >> 5, c4 = idx & 31;
    long long gr = rowBase + row;
    float4 v = make_float4(0.f, 0.f, 0.f, 0.f);
    if (gr < M) v = ((const float4*)A)[gr * 32 + c4];
    u16 hb[4] = {f2bf(v.x), f2bf(v.y), f2bf(v.z), f2bf(v.w)};
    u16 lb[4] = {f2bf(v.x - bf2f(hb[0])), f2bf(v.y - bf2f(hb[1])),
                 f2bf(v.z - bf2f(hb[2])), f2bf(v.w - bf2f(hb[3]))};
    *(uint2*)&ah[row * 136 + c4 * 4] = *(uint2*)hb;
    *(uint2*)&al[row * 136 + c4 * 4] = *(uint2*)lb;
  }
  __syncthreads();
  const int wid = tid >> 6, lane = tid & 63, lrow = lane & 15, lk = lane >> 4;
  bf16x8 af[4], alf[4];
  #pragma unroll
  for (int kc = 0; kc < 4; ++kc) {
    af[kc]  = *(const bf16x8*)&ah[(wid * 16 + lrow) * 136 + kc * 32 + lk * 8];
    alf[kc] = *(const bf16x8*)&al[(wid * 16 + lrow) * 136 + kc * 32 + lk * 8];
  }
  const u16* wfs[4] = {wf1, wfT, wf2, wf3};
  float* Cs[4] = {C0, C1, C2, C3};
  for (int m = 0; m < 4; ++m) {
    const u16* wf = wfs[m];
    float* C = Cs[m];
    f32x4 acc[8];
    #pragma unroll
    for (int t = 0; t < 8; ++t) acc[t] = (f32x4){0.f, 0.f, 0.f, 0.f};
    #pragma unroll
    for (int t = 0; t < 8; ++t) {
      #pragma unroll
      for (int kc = 0; kc < 4; ++kc) {
        bf16x8 bh = *(const bf16x8*)&wf[((t * 4 + kc) * 2) * 512 + lane * 8];
        bf16x8 bl = *(const bf16x8*)&wf[((t * 4 + kc) * 2 + 1) * 512 + lane * 8];
        acc[t] = __builtin_amdgcn_mfma_f32_16x16x32_bf16(af[kc],  bh, acc[t], 0, 0, 0);
        acc[t] = __builtin_amdgcn_mfma_f32_16x16x32_bf16(alf[kc], bh, acc[t], 0, 0, 0);
        acc[t] = __builtin_amdgcn_mfma_f32_16x16x32_bf16(af[kc],  bl, acc[t], 0, 0, 0);
      }
    }
    #pragma unroll
    for (int t = 0; t < 8; ++t) {
      int col = t * 16 + lrow;
      float bv = (m == 2) ? biases[128 + col] : (m == 3) ? biases[256 + col] : 0.f;
      #pragma unroll
      for (int r = 0; r < 4; ++r) {
        long long row = rowBase + wid * 16 + lk * 4 + r;
        if (row < M) C[row * 128 + col] = acc[t][r] + bv;
      }
    }
  }
  // hb1[row] = dot(A[row], b1) via hi+lo reconstruction from LDS (still valid).
  {
    int r = tid >> 2, p = tid & 3;
    long long row = rowBase + r;
    if (row < M) {
      float s = 0.f;
      #pragma unroll
      for (int k = 0; k < 32; ++k) {
        int kk = p * 32 + k;
        s += (bf2f(ah[r * 136 + kk]) + bf2f(al[r * 136 + kk])) * biases[kk];
      }
      s += __shfl_xor(s, 1);
      s += __shfl_xor(s, 2);
      if (p == 0) hb1[row] = s;
    }
  }
}

// ---------------------------------------------------------------------------
// Flash-style per-node edge aggregation. One wave per node. Online softmax
// over the node's CSR edge list; 2 channels per lane. Streams efeat rows once,
// gathers L3-resident hW1[src] rows. Writes X = sum(w*ef)/den, P = sum(w*hW1)/den.
// ---------------------------------------------------------------------------
__global__ __launch_bounds__(256)
void edge_agg(const float* __restrict__ efeat, const float* __restrict__ hW1,
              const float* __restrict__ hT1, const float* __restrict__ h,
              const float* __restrict__ hb1, const int* __restrict__ off,
              const int* __restrict__ eidx, const int* __restrict__ csrc,
              float* __restrict__ X, float* __restrict__ P, int N) {
  int node = blockIdx.x * 4 + (threadIdx.x >> 6);
  if (node >= N) return;
  const int lane = threadIdx.x & 63;
  const size_t nb = (size_t)node * 128 + 2 * lane;
  int s0 = off[node], s1 = off[node + 1];
  if (s1 == s0) {
    *(float2*)&X[nb] = make_float2(0.f, 0.f);
    *(float2*)&P[nb] = make_float2(0.f, 0.f);
    return;
  }
  const float2 hn = *(const float2*)&h[nb];
  const float2 ht = *(const float2*)&hT1[nb];
  const float hb = hb1[node];
  float mx = -3.4e38f, den = 0.f;
  float aEx = 0.f, aEy = 0.f, aHx = 0.f, aHy = 0.f;
  for (int base = s0; base < s1; base += 64) {
    int cnt = s1 - base;
    if (cnt > 64) cnt = 64;
    int me = 0, ms = 0;
    if (lane < cnt) { me = eidx[base + lane]; ms = csrc[base + lane]; }
    // 2-deep software pipeline: edge j+1's gathers issue under edge j's reduce.
    int e0 = __shfl(me, 0), sA = __shfl(ms, 0);
    float2 ef = *(const float2*)&efeat[(size_t)e0 * 128 + 2 * lane];
    float2 hw = *(const float2*)&hW1[(size_t)sA * 128 + 2 * lane];
    for (int j = 0; j < cnt; ++j) {
      float2 efc = ef, hwc = hw;
      if (j + 1 < cnt) {
        int e1 = __shfl(me, j + 1), sB = __shfl(ms, j + 1);
        ef = *(const float2*)&efeat[(size_t)e1 * 128 + 2 * lane];
        hw = *(const float2*)&hW1[(size_t)sB * 128 + 2 * lane];
      }
      float psum = efc.x * ht.x + efc.y * ht.y + hwc.x * hn.x + hwc.y * hn.y;
      #pragma unroll
      for (int o = 32; o > 0; o >>= 1) psum += __shfl_xor(psum, o);
      float score = psum + hb;                 // wave-uniform
      if (score > mx) {
        float r = __expf(mx - score);          // first edge: exp(-huge)=0
        den *= r; aEx *= r; aEy *= r; aHx *= r; aHy *= r;
        mx = score;
      }
      float w = __expf(score - mx);
      den += w;
      aEx += w * efc.x; aEy += w * efc.y;
      aHx += w * hwc.x; aHy += w * hwc.y;
    }
  }
  float inv = 1.f / den;                       // den >= 1 (max term present)
  *(float2*)&X[nb] = make_float2(aEx * inv, aEy * inv);
  *(float2*)&P[nb] = make_float2(aHx * inv, aHy * inv);
}

// ---------------------------------------------------------------------------
// Final node GEMM: out = leaky(y2 + b1 + P + X@W1), deg==0 -> leaky(y3).
// ---------------------------------------------------------------------------
__global__ __launch_bounds__(256)
void gemm_fin(const float* __restrict__ A,       // X
              const u16* __restrict__ wf,        // W1 frags
              const float* __restrict__ biases,  // b1 at [0..127]
              const float* __restrict__ y2, const float* __restrict__ y3,
              const float* __restrict__ P, const int* __restrict__ off,
              float* __restrict__ C, int M) {
  __shared__ u16 ah[64 * 136];
  __shared__ u16 al[64 * 136];
  const int tid = threadIdx.x;
  const long long rowBase = (long long)blockIdx.x * 64;
  #pragma unroll
  for (int it = 0; it < 8; ++it) {
    int idx = it * 256 + tid;
    int row = idx >> 5, c4 = idx & 31;
    long long gr = rowBase + row;
    float4 v = make_float4(0.f, 0.f, 0.f, 0.f);
    if (gr < M) v = ((const float4*)A)[gr * 32 + c4];
    u16 hb[4] = {f2bf(v.x), f2bf(v.y), f2bf(v.z), f2bf(v.w)};
    u16 lb[4] = {f2bf(v.x - bf2f(hb[0])), f2bf(v.y - bf2f(hb[1])),
                 f2bf(v.z - bf2f(hb[2])), f2bf(v.w - bf2f(hb[3]))};
    *(uint2*)&ah[row * 136 + c4 * 4] = *(uint2*)hb;
    *(uint2*)&al[row * 136 + c4 * 4] = *(uint2*)lb;
  }
  __syncthreads();
  const int wid = tid >> 6, lane = tid & 63, lrow = lane & 15, lk = lane >> 4;
  bf16x8 af[4], alf[4];
  #pragma unroll
  for (int kc = 0; kc < 4; ++kc) {
    af[kc]  = *(const bf16x8*)&ah[(wid * 16 + lrow) * 136 + kc * 32 + lk * 8];
    alf[kc] = *(const bf16x8*)&al[(wid * 16 + lrow) * 136 + kc * 32 + lk * 8];
  }
  f32x4 acc[8];
  #pragma unroll
  for (int t = 0; t < 8; ++t) acc[t] = (f32x4){0.f, 0.f, 0.f, 0.f};
  #pragma unroll
  for (int t = 0; t < 8; ++t) {
    #pragma unroll
    for (int kc = 0; kc < 4; ++kc) {
      bf16x8 bh = *(const bf16x8*)&wf[((t * 4 + kc) * 2) * 512 + lane * 8];
      bf16x8 bl = *(const bf16x8*)&wf[((t * 4 + kc) * 2 + 1) * 512 + lane * 8];
      acc[t] = __builtin_amdgcn_mfma_f32_16x16x32_bf16(af[kc],  bh, acc[t], 0, 0, 0);
      acc[t] = __builtin_amdgcn_mfma_f32_16x16x32_bf16(alf[kc], bh, acc[t], 0, 0, 0);
      acc[t] = __builtin_amdgcn_mfma_f32_16x16x32_bf16(af[kc],  bl, acc[t], 0, 0, 0);
    }
  }
  #pragma unroll
  for (int r = 0; r < 4; ++r) {
    long long row = rowBase + wid * 16 + lk * 4 + r;
    if (row >= M) continue;
    int dg = off[row + 1] - off[row];
    #pragma unroll
    for (int t = 0; t < 8; ++t) {
      int col = t * 16 + lrow;
      size_t o = (size_t)row * 128 + col;
      float v = dg ? (acc[t][r] + y2[o] + biases[col] + P[o]) : y3[o];
      v = v >= 0.f ? v : v * NEG_SLOPE;
      C[o] = v;
    }
  }
}

extern "C" void kernel_launch(void* const* d_in, const int* in_sizes, int n_in,
                              void* d_out, int out_size, void* d_ws, size_t ws_size,
                              hipStream_t stream) {
  const int D = 128;
  const int N = in_sizes[0] / D;
  const int E = in_sizes[1] / D;

  const float* node  = (const float*)d_in[0];
  const float* edgef = (const float*)d_in[1];
  const int* src = (const int*)d_in[2];
  const int* dst = (const int*)d_in[3];

  // workspace carve (~186 MB; prior CSR path required ~287 MB and ran, so fits)
  char* p = (char*)d_ws;
  u16*   wfrag = (u16*)p;   p += (size_t)8 * 32768 * 2;
  float* biasf = (float*)p; p += 4096;
  float* hW1   = (float*)p; p += (size_t)N * 512;
  float* hT1   = (float*)p; p += (size_t)N * 512;
  float* y2    = (float*)p; p += (size_t)N * 512;
  float* y3    = (float*)p; p += (size_t)N * 512;
  float* h1    = (float*)p; p += (size_t)N * 512;
  float* Xb    = (float*)p; p += (size_t)N * 512;
  float* Pb    = (float*)p; p += (size_t)N * 512;
  float* hb1   = (float*)p; p += (size_t)N * 4;
  int* deg     = (int*)p;   p += (size_t)N * 4;
  int* off     = (int*)p;   p += (size_t)(N + 256) * 4;
  int* cursor  = (int*)p;   p += (size_t)N * 4;
  int* bsum    = (int*)p;   p += 1024;
  int* eidx    = (int*)p;   p += (size_t)E * 4;
  int* csrc    = (int*)p;   p += (size_t)E * 4;
  (void)ws_size;

  prep_weights<<<8, 256, 0, stream>>>(
      (const float*)d_in[4],  (const float*)d_in[6],  (const float*)d_in[8],
      (const float*)d_in[10], (const float*)d_in[12], (const float*)d_in[14],
      (const float*)d_in[5],  (const float*)d_in[7],  (const float*)d_in[9],
      (const float*)d_in[11], (const float*)d_in[13], (const float*)d_in[15],
      wfrag, biasf);

  const int gN = (N + 63) / 64;
  const int eB = (E + 255) / 256;
  const int nb = (N + 1023) / 1024;

  hipMemsetAsync(deg, 0, (size_t)N * 4, stream);
  hist_k<<<eB, 256, 0, stream>>>(dst, deg, E);
  scan1<<<nb, 256, 0, stream>>>(deg, off, bsum, N);
  scan2<<<1, 256, 0, stream>>>(bsum, nb);
  scan3<<<(N + 256) / 256, 256, 0, stream>>>(off, bsum, cursor, N, E);
  scatter_k<<<eB, 256, 0, stream>>>(dst, src, cursor, eidx, csrc, E);

  for (int l = 0; l < 2; ++l) {
    const float* h = (l == 0) ? node : h1;
    float* hout = (l == 0) ? h1 : (float*)d_out;
    const u16* wf1 = wfrag + (size_t)(l * 3 + 0) * 32768;
    const u16* wf2 = wfrag + (size_t)(l * 3 + 1) * 32768;
    const u16* wf3 = wfrag + (size_t)(l * 3 + 2) * 32768;
    const u16* wfT = wfrag + (size_t)(6 + l) * 32768;
    const float* bset = biasf + l * 384;   // [b1|b2|b3] for this layer

    gemm_n4<<<gN, 256, 0, stream>>>(h, wf1, wfT, wf2, wf3, bset,
                                    hW1, hT1, y2, y3, hb1, N);
    edge_agg<<<(N + 3) / 4, 256, 0, stream>>>(edgef, hW1, hT1, h, hb1,
                                              off, eidx, csrc, Xb, Pb, N);
    gemm_fin<<<gN, 256, 0, stream>>>(Xb, wf1, bset, y2, y3, Pb, off, hout, N);
  }
}

// Round 2
// 892.613 us; speedup vs baseline: 1.4868x; 1.0444x over previous
//
#include <hip/hip_runtime.h>

// Round 7: second algebraic collapse.
//   sum_e w_e m_e / den = ((sum_e w_e (h[src]+ef)) / den) @ W1 + b1
//   score_e = <h[src]+ef, hT1[dst]> + hb1[dst],  hb1[dst] const per node
//             -> cancels in softmax -> dropped entirely.
// Per layer: gemm_n3t (hT1=h@W1^T, y2, y3) -> edge_agg (online softmax per
// node over CSR list; streams efeat, gathers h[src] (L3-resident); accumulates
// single U vector) -> gemm_fin (out = leaky(y2 + b1 + U@W1), deg0 -> y3).
// prep_weights spread over 64 blocks; y3 read predicated on deg==0.

typedef unsigned short u16;
typedef short bf16x8 __attribute__((ext_vector_type(8)));
typedef float f32x4 __attribute__((ext_vector_type(4)));

#define NEG_SLOPE 0.22916666666666666f

__device__ inline float bf2f(u16 h) { return __uint_as_float(((unsigned)h) << 16); }
__device__ inline u16 f2bf(float f) {
  unsigned u = __float_as_uint(f);
  u += 0x7fffu + ((u >> 16) & 1u);   // RNE
  return (u16)(u >> 16);
}

// ---------------------------------------------------------------------------
// Weight pre-split into MFMA-fragment-major bf16 hi/lo (B-frag for 16x16x32).
// Sets 0..5: W1_l0, W2_l0, W3_l0, W1_l1, W2_l1, W3_l1. Sets 6,7: W1^T l0/l1.
// 64 blocks: blockIdx>>3 = set, blockIdx&7 = q-chunk.
// ---------------------------------------------------------------------------
__global__ __launch_bounds__(256)
void prep_weights(const float* w0, const float* w1, const float* w2,
                  const float* w3, const float* w4, const float* w5,
                  const float* c0, const float* c1, const float* c2,
                  const float* c3, const float* c4, const float* c5,
                  u16* __restrict__ wf, float* __restrict__ bf) {
  int bid = blockIdx.x, tid = threadIdx.x;
  int b = bid >> 3, qc = (bid & 7) * 8;
  const float* Ws[8] = {w0, w1, w2, w3, w4, w5, w0, w3};
  const float* Cs[6] = {c0, c1, c2, c3, c4, c5};
  const float* W = Ws[b];
  const bool tr = (b >= 6);
  u16* out = wf + (size_t)b * 32768;
  #pragma unroll
  for (int qq = 0; qq < 8; ++qq) {
    int fi = tid * 64 + qc + qq;
    int t = fi >> 11, kc = (fi >> 9) & 3, lane = (fi >> 3) & 63, j = fi & 7;
    int k = kc * 32 + (lane >> 4) * 8 + j;
    int n = t * 16 + (lane & 15);
    float w = tr ? W[n * 128 + k] : W[k * 128 + n];
    u16 hi = f2bf(w);
    u16 lo = f2bf(w - bf2f(hi));
    int base = ((t * 4 + kc) * 2) * 512 + lane * 8 + j;
    out[base] = hi;
    out[base + 512] = lo;
  }
  if ((bid & 7) == 0 && b < 6 && tid < 128) bf[b * 128 + tid] = Cs[b][tid];
}

// ---------------------------------------------------------------------------
// CSR build: hist -> 3-step exclusive scan -> scatter (edge-id + src in CSR order).
// ---------------------------------------------------------------------------
__global__ __launch_bounds__(256)
void hist_k(const int* __restrict__ dst, int* __restrict__ deg, int E) {
  int i = blockIdx.x * 256 + threadIdx.x;
  int stride = gridDim.x * 256;
  for (; i < E; i += stride) atomicAdd(&deg[dst[i]], 1);
}

__global__ __launch_bounds__(256)
void scan1(const int* __restrict__ deg, int* __restrict__ off,
           int* __restrict__ bsum, int N) {
  __shared__ int sh[256];
  int b = blockIdx.x, t = threadIdx.x;
  int base = b * 1024 + t * 4;
  int v[4];
  #pragma unroll
  for (int i = 0; i < 4; ++i) v[i] = (base + i < N) ? deg[base + i] : 0;
  int s = v[0] + v[1] + v[2] + v[3];
  sh[t] = s;
  __syncthreads();
  for (int o = 1; o < 256; o <<= 1) {
    int x = (t >= o) ? sh[t - o] : 0;
    __syncthreads();
    sh[t] += x;
    __syncthreads();
  }
  int run = sh[t] - s;
  #pragma unroll
  for (int i = 0; i < 4; ++i) {
    if (base + i < N) off[base + i] = run;
    run += v[i];
  }
  if (t == 255) bsum[b] = sh[255];
}

__global__ void scan2(int* __restrict__ bsum, int nb) {
  __shared__ int sh[256];
  int t = threadIdx.x;
  int v = (t < nb) ? bsum[t] : 0;
  sh[t] = v;
  __syncthreads();
  for (int o = 1; o < 256; o <<= 1) {
    int x = (t >= o) ? sh[t - o] : 0;
    __syncthreads();
    sh[t] += x;
    __syncthreads();
  }
  if (t < nb) bsum[t] = sh[t] - v;
}

__global__ __launch_bounds__(256)
void scan3(int* __restrict__ off, const int* __restrict__ bsum,
           int* __restrict__ cursor, int N, int E) {
  int i = blockIdx.x * 256 + threadIdx.x;
  if (i < N) {
    int v = off[i] + bsum[i >> 10];
    off[i] = v;
    cursor[i] = v;
  } else if (i == N) {
    off[N] = E;
  }
}

__global__ __launch_bounds__(256)
void scatter_k(const int* __restrict__ dst, const int* __restrict__ src,
               int* __restrict__ cursor, int* __restrict__ eidx,
               int* __restrict__ csrc, int E) {
  int i = blockIdx.x * 256 + threadIdx.x;
  int stride = gridDim.x * 256;
  for (; i < E; i += stride) {
    int p = atomicAdd(&cursor[dst[i]], 1);
    eidx[p] = i;
    csrc[p] = src[i];
  }
}

// ---------------------------------------------------------------------------
// Fused node GEMMs: stage h once, apply 3 weight sets -> hT1, y2, y3.
// ---------------------------------------------------------------------------
__global__ __launch_bounds__(256)
void gemm_n3t(const float* __restrict__ A,
              const u16* __restrict__ wfT, const u16* __restrict__ wf2,
              const u16* __restrict__ wf3, const float* __restrict__ biases,
              float* __restrict__ C0, float* __restrict__ C1,
              float* __restrict__ C2, int M) {
  __shared__ u16 ah[64 * 136];
  __shared__ u16 al[64 * 136];
  const int tid = threadIdx.x;
  const long long rowBase = (long long)blockIdx.x * 64;
  #pragma unroll
  for (int it = 0; it < 8; ++it) {
    int idx = it * 256 + tid;
    int row = idx >> 5, c4 = idx & 31;
    long long gr = rowBase + row;
    float4 v = make_float4(0.f, 0.f, 0.f, 0.f);
    if (gr < M) v = ((const float4*)A)[gr * 32 + c4];
    u16 hb[4] = {f2bf(v.x), f2bf(v.y), f2bf(v.z), f2bf(v.w)};
    u16 lb[4] = {f2bf(v.x - bf2f(hb[0])), f2bf(v.y - bf2f(hb[1])),
                 f2bf(v.z - bf2f(hb[2])), f2bf(v.w - bf2f(hb[3]))};
    *(uint2*)&ah[row * 136 + c4 * 4] = *(uint2*)hb;
    *(uint2*)&al[row * 136 + c4 * 4] = *(uint2*)lb;
  }
  __syncthreads();
  const int wid = tid >> 6, lane = tid & 63, lrow = lane & 15, lk = lane >> 4;
  bf16x8 af[4], alf[4];
  #pragma unroll
  for (int kc = 0; kc < 4; ++kc) {
    af[kc]  = *(const bf16x8*)&ah[(wid * 16 + lrow) * 136 + kc * 32 + lk * 8];
    alf[kc] = *(const bf16x8*)&al[(wid * 16 + lrow) * 136 + kc * 32 + lk * 8];
  }
  const u16* wfs[3] = {wfT, wf2, wf3};
  float* Cs[3] = {C0, C1, C2};
  for (int m = 0; m < 3; ++m) {
    const u16* wf = wfs[m];
    float* C = Cs[m];
    f32x4 acc[8];
    #pragma unroll
    for (int t = 0; t < 8; ++t) acc[t] = (f32x4){0.f, 0.f, 0.f, 0.f};
    #pragma unroll
    for (int t = 0; t < 8; ++t) {
      #pragma unroll
      for (int kc = 0; kc < 4; ++kc) {
        bf16x8 bh = *(const bf16x8*)&wf[((t * 4 + kc) * 2) * 512 + lane * 8];
        bf16x8 bl = *(const bf16x8*)&wf[((t * 4 + kc) * 2 + 1) * 512 + lane * 8];
        acc[t] = __builtin_amdgcn_mfma_f32_16x16x32_bf16(af[kc],  bh, acc[t], 0, 0, 0);
        acc[t] = __builtin_amdgcn_mfma_f32_16x16x32_bf16(alf[kc], bh, acc[t], 0, 0, 0);
        acc[t] = __builtin_amdgcn_mfma_f32_16x16x32_bf16(af[kc],  bl, acc[t], 0, 0, 0);
      }
    }
    #pragma unroll
    for (int t = 0; t < 8; ++t) {
      int col = t * 16 + lrow;
      float bv = (m == 1) ? biases[128 + col] : (m == 2) ? biases[256 + col] : 0.f;
      #pragma unroll
      for (int r = 0; r < 4; ++r) {
        long long row = rowBase + wid * 16 + lk * 4 + r;
        if (row < M) C[row * 128 + col] = acc[t][r] + bv;
      }
    }
  }
}

// ---------------------------------------------------------------------------
// Flash-style per-node edge aggregation. One wave per node; online softmax.
// score_e = <h[src]+ef, hT1[dst]> (hb1[dst] term cancels in softmax).
// Accumulates single vector U = sum(w*(h[src]+ef))/den. 2 channels per lane.
// ---------------------------------------------------------------------------
__global__ __launch_bounds__(256)
void edge_agg(const float* __restrict__ efeat, const float* __restrict__ h,
              const float* __restrict__ hT1, const int* __restrict__ off,
              const int* __restrict__ eidx, const int* __restrict__ csrc,
              float* __restrict__ U, int N) {
  int node = blockIdx.x * 4 + (threadIdx.x >> 6);
  if (node >= N) return;
  const int lane = threadIdx.x & 63;
  const size_t nb = (size_t)node * 128 + 2 * lane;
  int s0 = off[node], s1 = off[node + 1];
  if (s1 == s0) {
    *(float2*)&U[nb] = make_float2(0.f, 0.f);
    return;
  }
  const float2 ht = *(const float2*)&hT1[nb];
  float mx = -3.4e38f, den = 0.f, ux = 0.f, uy = 0.f;
  for (int base = s0; base < s1; base += 64) {
    int cnt = s1 - base;
    if (cnt > 64) cnt = 64;
    int me = 0, ms = 0;
    if (lane < cnt) { me = eidx[base + lane]; ms = csrc[base + lane]; }
    // 2-deep software pipeline: edge j+1's gathers issue under edge j's reduce.
    int e0 = __shfl(me, 0), sA = __shfl(ms, 0);
    float2 ef = *(const float2*)&efeat[(size_t)e0 * 128 + 2 * lane];
    float2 hs = *(const float2*)&h[(size_t)sA * 128 + 2 * lane];
    for (int j = 0; j < cnt; ++j) {
      float vx = ef.x + hs.x, vy = ef.y + hs.y;
      if (j + 1 < cnt) {
        int e1 = __shfl(me, j + 1), sB = __shfl(ms, j + 1);
        ef = *(const float2*)&efeat[(size_t)e1 * 128 + 2 * lane];
        hs = *(const float2*)&h[(size_t)sB * 128 + 2 * lane];
      }
      float psum = vx * ht.x + vy * ht.y;
      #pragma unroll
      for (int o = 32; o > 0; o >>= 1) psum += __shfl_xor(psum, o);
      // psum == score, wave-uniform
      if (psum > mx) {
        float r = __expf(mx - psum);           // first edge: exp(-huge) = 0
        den *= r; ux *= r; uy *= r;
        mx = psum;
      }
      float w = __expf(psum - mx);
      den += w;
      ux += w * vx; uy += w * vy;
    }
  }
  float inv = 1.f / den;                       // den >= 1 (max term present)
  *(float2*)&U[nb] = make_float2(ux * inv, uy * inv);
}

// ---------------------------------------------------------------------------
// Final node GEMM: out = leaky(y2 + b1 + U@W1), deg==0 -> leaky(y3).
// ---------------------------------------------------------------------------
__global__ __launch_bounds__(256)
void gemm_fin(const float* __restrict__ A,       // U
              const u16* __restrict__ wf,        // W1 frags
              const float* __restrict__ biases,  // b1 at [0..127]
              const float* __restrict__ y2, const float* __restrict__ y3,
              const int* __restrict__ off, float* __restrict__ C, int M) {
  __shared__ u16 ah[64 * 136];
  __shared__ u16 al[64 * 136];
  const int tid = threadIdx.x;
  const long long rowBase = (long long)blockIdx.x * 64;
  #pragma unroll
  for (int it = 0; it < 8; ++it) {
    int idx = it * 256 + tid;
    int row = idx >> 5, c4 = idx & 31;
    long long gr = rowBase + row;
    float4 v = make_float4(0.f, 0.f, 0.f, 0.f);
    if (gr < M) v = ((const float4*)A)[gr * 32 + c4];
    u16 hb[4] = {f2bf(v.x), f2bf(v.y), f2bf(v.z), f2bf(v.w)};
    u16 lb[4] = {f2bf(v.x - bf2f(hb[0])), f2bf(v.y - bf2f(hb[1])),
                 f2bf(v.z - bf2f(hb[2])), f2bf(v.w - bf2f(hb[3]))};
    *(uint2*)&ah[row * 136 + c4 * 4] = *(uint2*)hb;
    *(uint2*)&al[row * 136 + c4 * 4] = *(uint2*)lb;
  }
  __syncthreads();
  const int wid = tid >> 6, lane = tid & 63, lrow = lane & 15, lk = lane >> 4;
  bf16x8 af[4], alf[4];
  #pragma unroll
  for (int kc = 0; kc < 4; ++kc) {
    af[kc]  = *(const bf16x8*)&ah[(wid * 16 + lrow) * 136 + kc * 32 + lk * 8];
    alf[kc] = *(const bf16x8*)&al[(wid * 16 + lrow) * 136 + kc * 32 + lk * 8];
  }
  f32x4 acc[8];
  #pragma unroll
  for (int t = 0; t < 8; ++t) acc[t] = (f32x4){0.f, 0.f, 0.f, 0.f};
  #pragma unroll
  for (int t = 0; t < 8; ++t) {
    #pragma unroll
    for (int kc = 0; kc < 4; ++kc) {
      bf16x8 bh = *(const bf16x8*)&wf[((t * 4 + kc) * 2) * 512 + lane * 8];
      bf16x8 bl = *(const bf16x8*)&wf[((t * 4 + kc) * 2 + 1) * 512 + lane * 8];
      acc[t] = __builtin_amdgcn_mfma_f32_16x16x32_bf16(af[kc],  bh, acc[t], 0, 0, 0);
      acc[t] = __builtin_amdgcn_mfma_f32_16x16x32_bf16(alf[kc], bh, acc[t], 0, 0, 0);
      acc[t] = __builtin_amdgcn_mfma_f32_16x16x32_bf16(af[kc],  bl, acc[t], 0, 0, 0);
    }
  }
  #pragma unroll
  for (int r = 0; r < 4; ++r) {
    long long row = rowBase + wid * 16 + lk * 4 + r;
    if (row >= M) continue;
    int dg = off[row + 1] - off[row];
    #pragma unroll
    for (int t = 0; t < 8; ++t) {
      int col = t * 16 + lrow;
      size_t o = (size_t)row * 128 + col;
      float v;
      if (dg) v = acc[t][r] + y2[o] + biases[col];
      else    v = y3[o];
      v = v >= 0.f ? v : v * NEG_SLOPE;
      C[o] = v;
    }
  }
}

extern "C" void kernel_launch(void* const* d_in, const int* in_sizes, int n_in,
                              void* d_out, int out_size, void* d_ws, size_t ws_size,
                              hipStream_t stream) {
  const int D = 128;
  const int N = in_sizes[0] / D;
  const int E = in_sizes[1] / D;

  const float* node  = (const float*)d_in[0];
  const float* edgef = (const float*)d_in[1];
  const int* src = (const int*)d_in[2];
  const int* dst = (const int*)d_in[3];

  // workspace carve (~134 MB)
  char* p = (char*)d_ws;
  u16*   wfrag = (u16*)p;   p += (size_t)8 * 32768 * 2;
  float* biasf = (float*)p; p += 4096;
  float* hT1   = (float*)p; p += (size_t)N * 512;
  float* y2    = (float*)p; p += (size_t)N * 512;
  float* y3    = (float*)p; p += (size_t)N * 512;
  float* h1    = (float*)p; p += (size_t)N * 512;
  float* Ub    = (float*)p; p += (size_t)N * 512;
  int* deg     = (int*)p;   p += (size_t)N * 4;
  int* off     = (int*)p;   p += (size_t)(N + 256) * 4;
  int* cursor  = (int*)p;   p += (size_t)N * 4;
  int* bsum    = (int*)p;   p += 1024;
  int* eidx    = (int*)p;   p += (size_t)E * 4;
  int* csrc    = (int*)p;   p += (size_t)E * 4;
  (void)ws_size;

  prep_weights<<<64, 256, 0, stream>>>(
      (const float*)d_in[4],  (const float*)d_in[6],  (const float*)d_in[8],
      (const float*)d_in[10], (const float*)d_in[12], (const float*)d_in[14],
      (const float*)d_in[5],  (const float*)d_in[7],  (const float*)d_in[9],
      (const float*)d_in[11], (const float*)d_in[13], (const float*)d_in[15],
      wfrag, biasf);

  const int gN = (N + 63) / 64;
  const int eB = (E + 255) / 256;
  const int nb = (N + 1023) / 1024;

  hipMemsetAsync(deg, 0, (size_t)N * 4, stream);
  hist_k<<<eB, 256, 0, stream>>>(dst, deg, E);
  scan1<<<nb, 256, 0, stream>>>(deg, off, bsum, N);
  scan2<<<1, 256, 0, stream>>>(bsum, nb);
  scan3<<<(N + 256) / 256, 256, 0, stream>>>(off, bsum, cursor, N, E);
  scatter_k<<<eB, 256, 0, stream>>>(dst, src, cursor, eidx, csrc, E);

  for (int l = 0; l < 2; ++l) {
    const float* h = (l == 0) ? node : h1;
    float* hout = (l == 0) ? h1 : (float*)d_out;
    const u16* wf1 = wfrag + (size_t)(l * 3 + 0) * 32768;
    const u16* wf2 = wfrag + (size_t)(l * 3 + 1) * 32768;
    const u16* wf3 = wfrag + (size_t)(l * 3 + 2) * 32768;
    const u16* wfT = wfrag + (size_t)(6 + l) * 32768;
    const float* bset = biasf + l * 384;   // [b1|b2|b3] for this layer

    gemm_n3t<<<gN, 256, 0, stream>>>(h, wfT, wf2, wf3, bset, hT1, y2, y3, N);
    edge_agg<<<(N + 3) / 4, 256, 0, stream>>>(edgef, h, hT1, off, eidx, csrc,
                                              Ub, N);
    gemm_fin<<<gN, 256, 0, stream>>>(Ub, wf1, bset, y2, y3, off, hout, N);
  }
}

// Round 3
// 797.719 us; speedup vs baseline: 1.6637x; 1.1190x over previous
//
#include <hip/hip_runtime.h>

// Round 8: edge_agg rewritten as 4-edge-parallel (16 lanes/edge, float4 x2 per
// lane), two-level prefetch pipeline (idx one step ahead of rows, rows one step
// ahead of compute), nontemporal efeat loads (protect h/hT1 in L3).
// gemm_n3t skips the y3 GEMM for blocks without deg-0 rows (nearly all).
// Algebra unchanged from round 7:
//   score_e = <h[src]+ef, hT1[dst]>   (hb1[dst] cancels in softmax)
//   U = sum(w*(h[src]+ef))/den ;  out = leaky(y2 + b1 + U@W1), deg0 -> y3.

typedef unsigned short u16;
typedef short bf16x8 __attribute__((ext_vector_type(8)));
typedef float f32x4 __attribute__((ext_vector_type(4)));

#define NEG_SLOPE 0.22916666666666666f

__device__ inline float bf2f(u16 h) { return __uint_as_float(((unsigned)h) << 16); }
__device__ inline u16 f2bf(float f) {
  unsigned u = __float_as_uint(f);
  u += 0x7fffu + ((u >> 16) & 1u);   // RNE
  return (u16)(u >> 16);
}

// ---------------------------------------------------------------------------
// Weight pre-split into MFMA-fragment-major bf16 hi/lo (B-frag for 16x16x32).
// Sets 0..5: W1_l0, W2_l0, W3_l0, W1_l1, W2_l1, W3_l1. Sets 6,7: W1^T l0/l1.
// 64 blocks: blockIdx>>3 = set, blockIdx&7 = q-chunk.
// ---------------------------------------------------------------------------
__global__ __launch_bounds__(256)
void prep_weights(const float* w0, const float* w1, const float* w2,
                  const float* w3, const float* w4, const float* w5,
                  const float* c0, const float* c1, const float* c2,
                  const float* c3, const float* c4, const float* c5,
                  u16* __restrict__ wf, float* __restrict__ bf) {
  int bid = blockIdx.x, tid = threadIdx.x;
  int b = bid >> 3, qc = (bid & 7) * 8;
  const float* Ws[8] = {w0, w1, w2, w3, w4, w5, w0, w3};
  const float* Cs[6] = {c0, c1, c2, c3, c4, c5};
  const float* W = Ws[b];
  const bool tr = (b >= 6);
  u16* out = wf + (size_t)b * 32768;
  #pragma unroll
  for (int qq = 0; qq < 8; ++qq) {
    int fi = tid * 64 + qc + qq;
    int t = fi >> 11, kc = (fi >> 9) & 3, lane = (fi >> 3) & 63, j = fi & 7;
    int k = kc * 32 + (lane >> 4) * 8 + j;
    int n = t * 16 + (lane & 15);
    float w = tr ? W[n * 128 + k] : W[k * 128 + n];
    u16 hi = f2bf(w);
    u16 lo = f2bf(w - bf2f(hi));
    int base = ((t * 4 + kc) * 2) * 512 + lane * 8 + j;
    out[base] = hi;
    out[base + 512] = lo;
  }
  if ((bid & 7) == 0 && b < 6 && tid < 128) bf[b * 128 + tid] = Cs[b][tid];
}

// ---------------------------------------------------------------------------
// CSR build: hist -> 3-step exclusive scan -> scatter (edge-id + src in CSR order).
// ---------------------------------------------------------------------------
__global__ __launch_bounds__(256)
void hist_k(const int* __restrict__ dst, int* __restrict__ deg, int E) {
  int i = blockIdx.x * 256 + threadIdx.x;
  int stride = gridDim.x * 256;
  for (; i < E; i += stride) atomicAdd(&deg[dst[i]], 1);
}

__global__ __launch_bounds__(256)
void scan1(const int* __restrict__ deg, int* __restrict__ off,
           int* __restrict__ bsum, int N) {
  __shared__ int sh[256];
  int b = blockIdx.x, t = threadIdx.x;
  int base = b * 1024 + t * 4;
  int v[4];
  #pragma unroll
  for (int i = 0; i < 4; ++i) v[i] = (base + i < N) ? deg[base + i] : 0;
  int s = v[0] + v[1] + v[2] + v[3];
  sh[t] = s;
  __syncthreads();
  for (int o = 1; o < 256; o <<= 1) {
    int x = (t >= o) ? sh[t - o] : 0;
    __syncthreads();
    sh[t] += x;
    __syncthreads();
  }
  int run = sh[t] - s;
  #pragma unroll
  for (int i = 0; i < 4; ++i) {
    if (base + i < N) off[base + i] = run;
    run += v[i];
  }
  if (t == 255) bsum[b] = sh[255];
}

__global__ void scan2(int* __restrict__ bsum, int nb) {
  __shared__ int sh[256];
  int t = threadIdx.x;
  int v = (t < nb) ? bsum[t] : 0;
  sh[t] = v;
  __syncthreads();
  for (int o = 1; o < 256; o <<= 1) {
    int x = (t >= o) ? sh[t - o] : 0;
    __syncthreads();
    sh[t] += x;
    __syncthreads();
  }
  if (t < nb) bsum[t] = sh[t] - v;
}

__global__ __launch_bounds__(256)
void scan3(int* __restrict__ off, const int* __restrict__ bsum,
           int* __restrict__ cursor, int N, int E) {
  int i = blockIdx.x * 256 + threadIdx.x;
  if (i < N) {
    int v = off[i] + bsum[i >> 10];
    off[i] = v;
    cursor[i] = v;
  } else if (i == N) {
    off[N] = E;
  }
}

__global__ __launch_bounds__(256)
void scatter_k(const int* __restrict__ dst, const int* __restrict__ src,
               int* __restrict__ cursor, int* __restrict__ eidx,
               int* __restrict__ csrc, int E) {
  int i = blockIdx.x * 256 + threadIdx.x;
  int stride = gridDim.x * 256;
  for (; i < E; i += stride) {
    int p = atomicAdd(&cursor[dst[i]], 1);
    eidx[p] = i;
    csrc[p] = src[i];
  }
}

// ---------------------------------------------------------------------------
// Fused node GEMMs: stage h once, apply weight sets -> hT1, y2 (+ y3 only if
// this 64-row block contains a deg-0 node; Poisson(12) => almost never).
// ---------------------------------------------------------------------------
__global__ __launch_bounds__(256)
void gemm_n3t(const float* __restrict__ A,
              const u16* __restrict__ wfT, const u16* __restrict__ wf2,
              const u16* __restrict__ wf3, const float* __restrict__ biases,
              const int* __restrict__ off,
              float* __restrict__ C0, float* __restrict__ C1,
              float* __restrict__ C2, int M) {
  __shared__ u16 ah[64 * 136];
  __shared__ u16 al[64 * 136];
  __shared__ int anyDeg0;
  const int tid = threadIdx.x;
  const long long rowBase = (long long)blockIdx.x * 64;
  if (tid == 0) anyDeg0 = 0;
  __syncthreads();
  #pragma unroll
  for (int it = 0; it < 8; ++it) {
    int idx = it * 256 + tid;
    int row = idx >> 5, c4 = idx & 31;
    long long gr = rowBase + row;
    float4 v = make_float4(0.f, 0.f, 0.f, 0.f);
    if (gr < M) v = ((const float4*)A)[gr * 32 + c4];
    u16 hb[4] = {f2bf(v.x), f2bf(v.y), f2bf(v.z), f2bf(v.w)};
    u16 lb[4] = {f2bf(v.x - bf2f(hb[0])), f2bf(v.y - bf2f(hb[1])),
                 f2bf(v.z - bf2f(hb[2])), f2bf(v.w - bf2f(hb[3]))};
    *(uint2*)&ah[row * 136 + c4 * 4] = *(uint2*)hb;
    *(uint2*)&al[row * 136 + c4 * 4] = *(uint2*)lb;
  }
  if (tid < 64) {
    long long r = rowBase + tid;
    if (r < M && off[r + 1] == off[r]) anyDeg0 = 1;
  }
  __syncthreads();
  const int nsets = anyDeg0 ? 3 : 2;
  const int wid = tid >> 6, lane = tid & 63, lrow = lane & 15, lk = lane >> 4;
  bf16x8 af[4], alf[4];
  #pragma unroll
  for (int kc = 0; kc < 4; ++kc) {
    af[kc]  = *(const bf16x8*)&ah[(wid * 16 + lrow) * 136 + kc * 32 + lk * 8];
    alf[kc] = *(const bf16x8*)&al[(wid * 16 + lrow) * 136 + kc * 32 + lk * 8];
  }
  const u16* wfs[3] = {wfT, wf2, wf3};
  float* Cs[3] = {C0, C1, C2};
  for (int m = 0; m < nsets; ++m) {
    const u16* wf = wfs[m];
    float* C = Cs[m];
    f32x4 acc[8];
    #pragma unroll
    for (int t = 0; t < 8; ++t) acc[t] = (f32x4){0.f, 0.f, 0.f, 0.f};
    #pragma unroll
    for (int t = 0; t < 8; ++t) {
      #pragma unroll
      for (int kc = 0; kc < 4; ++kc) {
        bf16x8 bh = *(const bf16x8*)&wf[((t * 4 + kc) * 2) * 512 + lane * 8];
        bf16x8 bl = *(const bf16x8*)&wf[((t * 4 + kc) * 2 + 1) * 512 + lane * 8];
        acc[t] = __builtin_amdgcn_mfma_f32_16x16x32_bf16(af[kc],  bh, acc[t], 0, 0, 0);
        acc[t] = __builtin_amdgcn_mfma_f32_16x16x32_bf16(alf[kc], bh, acc[t], 0, 0, 0);
        acc[t] = __builtin_amdgcn_mfma_f32_16x16x32_bf16(af[kc],  bl, acc[t], 0, 0, 0);
      }
    }
    #pragma unroll
    for (int t = 0; t < 8; ++t) {
      int col = t * 16 + lrow;
      float bv = (m == 1) ? biases[128 + col] : (m == 2) ? biases[256 + col] : 0.f;
      #pragma unroll
      for (int r = 0; r < 4; ++r) {
        long long row = rowBase + wid * 16 + lk * 4 + r;
        if (row < M) C[row * 128 + col] = acc[t][r] + bv;
      }
    }
  }
}

// ---------------------------------------------------------------------------
// 4-edge-parallel flash aggregation. One wave per node; 4 groups of 16 lanes,
// each group owns one edge per step; 8 channels/lane (2 x float4).
// Two-level prefetch: edge indices one step ahead of row loads, row loads one
// step ahead of compute. efeat loaded nontemporal (read-once stream).
// ---------------------------------------------------------------------------
__global__ __launch_bounds__(256)
void edge_agg(const float* __restrict__ efeat, const float* __restrict__ h,
              const float* __restrict__ hT1, const int* __restrict__ off,
              const int* __restrict__ eidx, const int* __restrict__ csrc,
              float* __restrict__ U, int N) {
  int node = blockIdx.x * 4 + (threadIdx.x >> 6);
  if (node >= N) return;
  const int lane = threadIdx.x & 63;
  const int g = lane >> 4, cl = lane & 15;
  const size_t nb = (size_t)node * 128 + (size_t)cl * 8;
  const int s0 = off[node];
  const int cnt = off[node + 1] - s0;
  if (cnt == 0) {
    if (g == 0) {
      *(f32x4*)&U[nb]     = (f32x4){0.f, 0.f, 0.f, 0.f};
      *(f32x4*)&U[nb + 4] = (f32x4){0.f, 0.f, 0.f, 0.f};
    }
    return;
  }
  const f32x4 ht0 = *(const f32x4*)&hT1[nb];
  const f32x4 ht1 = *(const f32x4*)&hT1[nb + 4];
  float mx = -3.4e38f, den = 0.f;
  f32x4 u0 = (f32x4){0.f, 0.f, 0.f, 0.f};
  f32x4 u1 = (f32x4){0.f, 0.f, 0.f, 0.f};
  const int nsteps = (cnt + 3) >> 2;

  // prologue: rows for step 0, indices for step 1
  bool actC = (g < cnt);
  {
    int i0 = s0 + (actC ? g : 0);
    int eC = eidx[i0], sC = csrc[i0];
    const f32x4* efp = (const f32x4*)(efeat + (size_t)eC * 128) + cl * 2;
    const f32x4* hp  = (const f32x4*)(h + (size_t)sC * 128) + cl * 2;
    f32x4 fC0 = __builtin_nontemporal_load(efp);
    f32x4 fC1 = __builtin_nontemporal_load(efp + 1);
    f32x4 hC0 = hp[0], hC1 = hp[1];

    int j1 = 4 + g;
    bool actN = (j1 < cnt);
    int i1 = s0 + (actN ? j1 : 0);
    int eN = eidx[i1], sN = csrc[i1];

    for (int k = 0; k < nsteps; ++k) {
      // issue rows for step k+1 (indices already resident)
      const f32x4* efn = (const f32x4*)(efeat + (size_t)eN * 128) + cl * 2;
      const f32x4* hn  = (const f32x4*)(h + (size_t)sN * 128) + cl * 2;
      f32x4 fN0 = __builtin_nontemporal_load(efn);
      f32x4 fN1 = __builtin_nontemporal_load(efn + 1);
      f32x4 hN0 = hn[0], hN1 = hn[1];
      // prefetch indices for step k+2
      int j2 = (k + 2) * 4 + g;
      bool act2 = (j2 < cnt);
      int i2 = s0 + (act2 ? j2 : 0);
      int e2 = eidx[i2], s2 = csrc[i2];

      // compute step k
      f32x4 v0 = fC0 + hC0, v1 = fC1 + hC1;
      float ps = v0[0] * ht0[0] + v0[1] * ht0[1] + v0[2] * ht0[2] + v0[3] * ht0[3]
               + v1[0] * ht1[0] + v1[1] * ht1[1] + v1[2] * ht1[2] + v1[3] * ht1[3];
      ps += __shfl_xor(ps, 1);
      ps += __shfl_xor(ps, 2);
      ps += __shfl_xor(ps, 4);
      ps += __shfl_xor(ps, 8);
      float s = actC ? ps : -3.4e38f;
      float m2 = fmaxf(s, __shfl_xor(s, 16));
      float m4 = fmaxf(m2, __shfl_xor(m2, 32));
      float mxn = fmaxf(mx, m4);
      float r = __expf(mx - mxn);          // first step: exp(-huge) = 0
      float w = __expf(s - mxn);           // inactive group: 0
      float w2 = w + __shfl_xor(w, 16);
      float w4 = w2 + __shfl_xor(w2, 32);
      den = den * r + w4;
      u0 = u0 * r + w * v0;
      u1 = u1 * r + w * v1;
      mx = mxn;
      // rotate pipeline
      fC0 = fN0; fC1 = fN1; hC0 = hN0; hC1 = hN1; actC = actN;
      eN = e2; sN = s2; actN = act2;
    }
  }
  // cross-group sum of U partials
  #pragma unroll
  for (int c = 0; c < 4; ++c) {
    u0[c] += __shfl_xor(u0[c], 16); u0[c] += __shfl_xor(u0[c], 32);
    u1[c] += __shfl_xor(u1[c], 16); u1[c] += __shfl_xor(u1[c], 32);
  }
  float inv = 1.f / den;                   // den >= 1 (max term present)
  if (g == 0) {
    *(f32x4*)&U[nb]     = u0 * inv;
    *(f32x4*)&U[nb + 4] = u1 * inv;
  }
}

// ---------------------------------------------------------------------------
// Final node GEMM: out = leaky(y2 + b1 + U@W1), deg==0 -> leaky(y3).
// ---------------------------------------------------------------------------
__global__ __launch_bounds__(256)
void gemm_fin(const float* __restrict__ A,       // U
              const u16* __restrict__ wf,        // W1 frags
              const float* __restrict__ biases,  // b1 at [0..127]
              const float* __restrict__ y2, const float* __restrict__ y3,
              const int* __restrict__ off, float* __restrict__ C, int M) {
  __shared__ u16 ah[64 * 136];
  __shared__ u16 al[64 * 136];
  const int tid = threadIdx.x;
  const long long rowBase = (long long)blockIdx.x * 64;
  #pragma unroll
  for (int it = 0; it < 8; ++it) {
    int idx = it * 256 + tid;
    int row = idx >> 5, c4 = idx & 31;
    long long gr = rowBase + row;
    float4 v = make_float4(0.f, 0.f, 0.f, 0.f);
    if (gr < M) v = ((const float4*)A)[gr * 32 + c4];
    u16 hb[4] = {f2bf(v.x), f2bf(v.y), f2bf(v.z), f2bf(v.w)};
    u16 lb[4] = {f2bf(v.x - bf2f(hb[0])), f2bf(v.y - bf2f(hb[1])),
                 f2bf(v.z - bf2f(hb[2])), f2bf(v.w - bf2f(hb[3]))};
    *(uint2*)&ah[row * 136 + c4 * 4] = *(uint2*)hb;
    *(uint2*)&al[row * 136 + c4 * 4] = *(uint2*)lb;
  }
  __syncthreads();
  const int wid = tid >> 6, lane = tid & 63, lrow = lane & 15, lk = lane >> 4;
  bf16x8 af[4], alf[4];
  #pragma unroll
  for (int kc = 0; kc < 4; ++kc) {
    af[kc]  = *(const bf16x8*)&ah[(wid * 16 + lrow) * 136 + kc * 32 + lk * 8];
    alf[kc] = *(const bf16x8*)&al[(wid * 16 + lrow) * 136 + kc * 32 + lk * 8];
  }
  f32x4 acc[8];
  #pragma unroll
  for (int t = 0; t < 8; ++t) acc[t] = (f32x4){0.f, 0.f, 0.f, 0.f};
  #pragma unroll
  for (int t = 0; t < 8; ++t) {
    #pragma unroll
    for (int kc = 0; kc < 4; ++kc) {
      bf16x8 bh = *(const bf16x8*)&wf[((t * 4 + kc) * 2) * 512 + lane * 8];
      bf16x8 bl = *(const bf16x8*)&wf[((t * 4 + kc) * 2 + 1) * 512 + lane * 8];
      acc[t] = __builtin_amdgcn_mfma_f32_16x16x32_bf16(af[kc],  bh, acc[t], 0, 0, 0);
      acc[t] = __builtin_amdgcn_mfma_f32_16x16x32_bf16(alf[kc], bh, acc[t], 0, 0, 0);
      acc[t] = __builtin_amdgcn_mfma_f32_16x16x32_bf16(af[kc],  bl, acc[t], 0, 0, 0);
    }
  }
  #pragma unroll
  for (int r = 0; r < 4; ++r) {
    long long row = rowBase + wid * 16 + lk * 4 + r;
    if (row >= M) continue;
    int dg = off[row + 1] - off[row];
    #pragma unroll
    for (int t = 0; t < 8; ++t) {
      int col = t * 16 + lrow;
      size_t o = (size_t)row * 128 + col;
      float v;
      if (dg) v = acc[t][r] + y2[o] + biases[col];
      else    v = y3[o];
      v = v >= 0.f ? v : v * NEG_SLOPE;
      C[o] = v;
    }
  }
}

extern "C" void kernel_launch(void* const* d_in, const int* in_sizes, int n_in,
                              void* d_out, int out_size, void* d_ws, size_t ws_size,
                              hipStream_t stream) {
  const int D = 128;
  const int N = in_sizes[0] / D;
  const int E = in_sizes[1] / D;

  const float* node  = (const float*)d_in[0];
  const float* edgef = (const float*)d_in[1];
  const int* src = (const int*)d_in[2];
  const int* dst = (const int*)d_in[3];

  // workspace carve (~134 MB)
  char* p = (char*)d_ws;
  u16*   wfrag = (u16*)p;   p += (size_t)8 * 32768 * 2;
  float* biasf = (float*)p; p += 4096;
  float* hT1   = (float*)p; p += (size_t)N * 512;
  float* y2    = (float*)p; p += (size_t)N * 512;
  float* y3    = (float*)p; p += (size_t)N * 512;
  float* h1    = (float*)p; p += (size_t)N * 512;
  float* Ub    = (float*)p; p += (size_t)N * 512;
  int* deg     = (int*)p;   p += (size_t)N * 4;
  int* off     = (int*)p;   p += (size_t)(N + 256) * 4;
  int* cursor  = (int*)p;   p += (size_t)N * 4;
  int* bsum    = (int*)p;   p += 1024;
  int* eidx    = (int*)p;   p += (size_t)E * 4;
  int* csrc    = (int*)p;   p += (size_t)E * 4;
  (void)ws_size;

  prep_weights<<<64, 256, 0, stream>>>(
      (const float*)d_in[4],  (const float*)d_in[6],  (const float*)d_in[8],
      (const float*)d_in[10], (const float*)d_in[12], (const float*)d_in[14],
      (const float*)d_in[5],  (const float*)d_in[7],  (const float*)d_in[9],
      (const float*)d_in[11], (const float*)d_in[13], (const float*)d_in[15],
      wfrag, biasf);

  const int gN = (N + 63) / 64;
  const int eB = (E + 255) / 256;
  const int nb = (N + 1023) / 1024;

  hipMemsetAsync(deg, 0, (size_t)N * 4, stream);
  hist_k<<<eB, 256, 0, stream>>>(dst, deg, E);
  scan1<<<nb, 256, 0, stream>>>(deg, off, bsum, N);
  scan2<<<1, 256, 0, stream>>>(bsum, nb);
  scan3<<<(N + 256) / 256, 256, 0, stream>>>(off, bsum, cursor, N, E);
  scatter_k<<<eB, 256, 0, stream>>>(dst, src, cursor, eidx, csrc, E);

  for (int l = 0; l < 2; ++l) {
    const float* h = (l == 0) ? node : h1;
    float* hout = (l == 0) ? h1 : (float*)d_out;
    const u16* wf1 = wfrag + (size_t)(l * 3 + 0) * 32768;
    const u16* wf2 = wfrag + (size_t)(l * 3 + 1) * 32768;
    const u16* wf3 = wfrag + (size_t)(l * 3 + 2) * 32768;
    const u16* wfT = wfrag + (size_t)(6 + l) * 32768;
    const float* bset = biasf + l * 384;   // [b1|b2|b3] for this layer

    gemm_n3t<<<gN, 256, 0, stream>>>(h, wfT, wf2, wf3, bset, off, hT1, y2, y3, N);
    edge_agg<<<(N + 3) / 4, 256, 0, stream>>>(edgef, h, hT1, off, eidx, csrc,
                                              Ub, N);
    gemm_fin<<<gN, 256, 0, stream>>>(Ub, wf1, bset, y2, y3, off, hout, N);
  }
}

// Round 4
// 797.053 us; speedup vs baseline: 1.6651x; 1.0008x over previous
//
#include <hip/hip_runtime.h>

// Round 9: edge_agg restructured as one 16-lane group per node (4 independent
// nodes per wave -> no cross-group softmax coupling, 1 shfl-chain serves 4
// edges), depth-4 named-slot load pipeline, int2-fused index array prefetched
// one trip ahead, deferred-max rescale (threshold 8).
// Algebra unchanged from round 7:
//   score_e = <h[src]+ef, hT1[dst]>   (hb1[dst] cancels in softmax)
//   U = sum(w*(h[src]+ef))/den ;  out = leaky(y2 + b1 + U@W1), deg0 -> y3.

typedef unsigned short u16;
typedef short bf16x8 __attribute__((ext_vector_type(8)));
typedef float f32x4 __attribute__((ext_vector_type(4)));

#define NEG_SLOPE 0.22916666666666666f

__device__ inline float bf2f(u16 h) { return __uint_as_float(((unsigned)h) << 16); }
__device__ inline u16 f2bf(float f) {
  unsigned u = __float_as_uint(f);
  u += 0x7fffu + ((u >> 16) & 1u);   // RNE
  return (u16)(u >> 16);
}

// ---------------------------------------------------------------------------
// Weight pre-split into MFMA-fragment-major bf16 hi/lo (B-frag for 16x16x32).
// Sets 0..5: W1_l0, W2_l0, W3_l0, W1_l1, W2_l1, W3_l1. Sets 6,7: W1^T l0/l1.
// 64 blocks: blockIdx>>3 = set, blockIdx&7 = q-chunk.
// ---------------------------------------------------------------------------
__global__ __launch_bounds__(256)
void prep_weights(const float* w0, const float* w1, const float* w2,
                  const float* w3, const float* w4, const float* w5,
                  const float* c0, const float* c1, const float* c2,
                  const float* c3, const float* c4, const float* c5,
                  u16* __restrict__ wf, float* __restrict__ bf) {
  int bid = blockIdx.x, tid = threadIdx.x;
  int b = bid >> 3, qc = (bid & 7) * 8;
  const float* Ws[8] = {w0, w1, w2, w3, w4, w5, w0, w3};
  const float* Cs[6] = {c0, c1, c2, c3, c4, c5};
  const float* W = Ws[b];
  const bool tr = (b >= 6);
  u16* out = wf + (size_t)b * 32768;
  #pragma unroll
  for (int qq = 0; qq < 8; ++qq) {
    int fi = tid * 64 + qc + qq;
    int t = fi >> 11, kc = (fi >> 9) & 3, lane = (fi >> 3) & 63, j = fi & 7;
    int k = kc * 32 + (lane >> 4) * 8 + j;
    int n = t * 16 + (lane & 15);
    float w = tr ? W[n * 128 + k] : W[k * 128 + n];
    u16 hi = f2bf(w);
    u16 lo = f2bf(w - bf2f(hi));
    int base = ((t * 4 + kc) * 2) * 512 + lane * 8 + j;
    out[base] = hi;
    out[base + 512] = lo;
  }
  if ((bid & 7) == 0 && b < 6 && tid < 128) bf[b * 128 + tid] = Cs[b][tid];
}

// ---------------------------------------------------------------------------
// CSR build: hist -> 3-step exclusive scan -> scatter (fused (edge-id,src) pairs).
// ---------------------------------------------------------------------------
__global__ __launch_bounds__(256)
void hist_k(const int* __restrict__ dst, int* __restrict__ deg, int E) {
  int i = blockIdx.x * 256 + threadIdx.x;
  int stride = gridDim.x * 256;
  for (; i < E; i += stride) atomicAdd(&deg[dst[i]], 1);
}

__global__ __launch_bounds__(256)
void scan1(const int* __restrict__ deg, int* __restrict__ off,
           int* __restrict__ bsum, int N) {
  __shared__ int sh[256];
  int b = blockIdx.x, t = threadIdx.x;
  int base = b * 1024 + t * 4;
  int v[4];
  #pragma unroll
  for (int i = 0; i < 4; ++i) v[i] = (base + i < N) ? deg[base + i] : 0;
  int s = v[0] + v[1] + v[2] + v[3];
  sh[t] = s;
  __syncthreads();
  for (int o = 1; o < 256; o <<= 1) {
    int x = (t >= o) ? sh[t - o] : 0;
    __syncthreads();
    sh[t] += x;
    __syncthreads();
  }
  int run = sh[t] - s;
  #pragma unroll
  for (int i = 0; i < 4; ++i) {
    if (base + i < N) off[base + i] = run;
    run += v[i];
  }
  if (t == 255) bsum[b] = sh[255];
}

__global__ void scan2(int* __restrict__ bsum, int nb) {
  __shared__ int sh[256];
  int t = threadIdx.x;
  int v = (t < nb) ? bsum[t] : 0;
  sh[t] = v;
  __syncthreads();
  for (int o = 1; o < 256; o <<= 1) {
    int x = (t >= o) ? sh[t - o] : 0;
    __syncthreads();
    sh[t] += x;
    __syncthreads();
  }
  if (t < nb) bsum[t] = sh[t] - v;
}

__global__ __launch_bounds__(256)
void scan3(int* __restrict__ off, const int* __restrict__ bsum,
           int* __restrict__ cursor, int N, int E) {
  int i = blockIdx.x * 256 + threadIdx.x;
  if (i < N) {
    int v = off[i] + bsum[i >> 10];
    off[i] = v;
    cursor[i] = v;
  } else if (i == N) {
    off[N] = E;
  }
}

__global__ __launch_bounds__(256)
void scatter_k(const int* __restrict__ dst, const int* __restrict__ src,
               int* __restrict__ cursor, int2* __restrict__ epair, int E) {
  int i = blockIdx.x * 256 + threadIdx.x;
  int stride = gridDim.x * 256;
  for (; i < E; i += stride) {
    int p = atomicAdd(&cursor[dst[i]], 1);
    epair[p] = make_int2(i, src[i]);
  }
}

// ---------------------------------------------------------------------------
// Fused node GEMMs: stage h once, apply weight sets -> hT1, y2 (+ y3 only if
// this 64-row block contains a deg-0 node; Poisson(12) => almost never).
// ---------------------------------------------------------------------------
__global__ __launch_bounds__(256)
void gemm_n3t(const float* __restrict__ A,
              const u16* __restrict__ wfT, const u16* __restrict__ wf2,
              const u16* __restrict__ wf3, const float* __restrict__ biases,
              const int* __restrict__ off,
              float* __restrict__ C0, float* __restrict__ C1,
              float* __restrict__ C2, int M) {
  __shared__ u16 ah[64 * 136];
  __shared__ u16 al[64 * 136];
  __shared__ int anyDeg0;
  const int tid = threadIdx.x;
  const long long rowBase = (long long)blockIdx.x * 64;
  if (tid == 0) anyDeg0 = 0;
  __syncthreads();
  #pragma unroll
  for (int it = 0; it < 8; ++it) {
    int idx = it * 256 + tid;
    int row = idx >> 5, c4 = idx & 31;
    long long gr = rowBase + row;
    float4 v = make_float4(0.f, 0.f, 0.f, 0.f);
    if (gr < M) v = ((const float4*)A)[gr * 32 + c4];
    u16 hb[4] = {f2bf(v.x), f2bf(v.y), f2bf(v.z), f2bf(v.w)};
    u16 lb[4] = {f2bf(v.x - bf2f(hb[0])), f2bf(v.y - bf2f(hb[1])),
                 f2bf(v.z - bf2f(hb[2])), f2bf(v.w - bf2f(hb[3]))};
    *(uint2*)&ah[row * 136 + c4 * 4] = *(uint2*)hb;
    *(uint2*)&al[row * 136 + c4 * 4] = *(uint2*)lb;
  }
  if (tid < 64) {
    long long r = rowBase + tid;
    if (r < M && off[r + 1] == off[r]) anyDeg0 = 1;
  }
  __syncthreads();
  const int nsets = anyDeg0 ? 3 : 2;
  const int wid = tid >> 6, lane = tid & 63, lrow = lane & 15, lk = lane >> 4;
  bf16x8 af[4], alf[4];
  #pragma unroll
  for (int kc = 0; kc < 4; ++kc) {
    af[kc]  = *(const bf16x8*)&ah[(wid * 16 + lrow) * 136 + kc * 32 + lk * 8];
    alf[kc] = *(const bf16x8*)&al[(wid * 16 + lrow) * 136 + kc * 32 + lk * 8];
  }
  const u16* wfs[3] = {wfT, wf2, wf3};
  float* Cs[3] = {C0, C1, C2};
  for (int m = 0; m < nsets; ++m) {
    const u16* wf = wfs[m];
    float* C = Cs[m];
    f32x4 acc[8];
    #pragma unroll
    for (int t = 0; t < 8; ++t) acc[t] = (f32x4){0.f, 0.f, 0.f, 0.f};
    #pragma unroll
    for (int t = 0; t < 8; ++t) {
      #pragma unroll
      for (int kc = 0; kc < 4; ++kc) {
        bf16x8 bh = *(const bf16x8*)&wf[((t * 4 + kc) * 2) * 512 + lane * 8];
        bf16x8 bl = *(const bf16x8*)&wf[((t * 4 + kc) * 2 + 1) * 512 + lane * 8];
        acc[t] = __builtin_amdgcn_mfma_f32_16x16x32_bf16(af[kc],  bh, acc[t], 0, 0, 0);
        acc[t] = __builtin_amdgcn_mfma_f32_16x16x32_bf16(alf[kc], bh, acc[t], 0, 0, 0);
        acc[t] = __builtin_amdgcn_mfma_f32_16x16x32_bf16(af[kc],  bl, acc[t], 0, 0, 0);
      }
    }
    #pragma unroll
    for (int t = 0; t < 8; ++t) {
      int col = t * 16 + lrow;
      float bv = (m == 1) ? biases[128 + col] : (m == 2) ? biases[256 + col] : 0.f;
      #pragma unroll
      for (int r = 0; r < 4; ++r) {
        long long row = rowBase + wid * 16 + lk * 4 + r;
        if (row < M) C[row * 128 + col] = acc[t][r] + bv;
      }
    }
  }
}

// ---------------------------------------------------------------------------
// Edge aggregation: one 16-lane group per node (16 nodes / 256-block).
// Independent online softmax per group; depth-4 named-slot pipeline; fused
// (eidx,src) int2 loads prefetched one trip ahead; deferred-max (thr=8).
// ---------------------------------------------------------------------------
__global__ __launch_bounds__(256)
void edge_agg(const float* __restrict__ efeat, const float* __restrict__ h,
              const float* __restrict__ hT1, const int* __restrict__ off,
              const int2* __restrict__ epair, float* __restrict__ U, int N) {
  const int node = blockIdx.x * 16 + (threadIdx.x >> 4);
  const int cl = threadIdx.x & 15;
  const bool valid = (node < N);
  const size_t nb = (size_t)node * 128 + (size_t)cl * 8;
  int s0 = 0, cnt = 0;
  if (valid) {
    s0 = off[node];
    cnt = off[node + 1] - s0;
  }
  // wave-max edge count (all lanes participate; invalid groups have cnt=0)
  int jm = cnt;
  jm = max(jm, __shfl_xor(jm, 16));
  jm = max(jm, __shfl_xor(jm, 32));

  f32x4 ht0 = (f32x4){0.f, 0.f, 0.f, 0.f}, ht1 = ht0;
  if (valid && cnt > 0) {
    ht0 = *(const f32x4*)&hT1[nb];
    ht1 = *(const f32x4*)&hT1[nb + 4];
  }

  f32x4 fA0, fA1, hA0, hA1, fB0, fB1, hB0, hB1;
  f32x4 fC0, fC1, hC0, hC1, fD0, fD1, hD0, hD1;
  int2 iA = make_int2(0, 0), iB = iA, iC = iA, iD = iA;

  // prologue: rows for edges 0..3, index prefetch for edges 4..7
  #define PRO(S, JJ)                                                          \
    if (JJ < cnt) {                                                           \
      int2 pr = epair[s0 + JJ];                                               \
      const f32x4* efp = (const f32x4*)(efeat + (size_t)pr.x * 128) + cl * 2; \
      f##S##0 = __builtin_nontemporal_load(efp);                              \
      f##S##1 = __builtin_nontemporal_load(efp + 1);                          \
      const f32x4* hp = (const f32x4*)(h + (size_t)pr.y * 128) + cl * 2;      \
      h##S##0 = hp[0]; h##S##1 = hp[1];                                       \
      if (JJ + 4 < cnt) i##S = epair[s0 + JJ + 4];                            \
    }
  PRO(A, 0) PRO(B, 1) PRO(C, 2) PRO(D, 3)
  #undef PRO

  float mx = -3.4e38f, den = 0.f;
  f32x4 u0 = (f32x4){0.f, 0.f, 0.f, 0.f}, u1 = u0;

  #define PROC(S, OFS) {                                                      \
    int je = j + OFS;                                                         \
    if (je < cnt) {                                                           \
      f32x4 v0 = f##S##0 + h##S##0, v1 = f##S##1 + h##S##1;                   \
      float ps = v0[0]*ht0[0] + v0[1]*ht0[1] + v0[2]*ht0[2] + v0[3]*ht0[3]    \
               + v1[0]*ht1[0] + v1[1]*ht1[1] + v1[2]*ht1[2] + v1[3]*ht1[3];   \
      ps += __shfl_xor(ps, 1); ps += __shfl_xor(ps, 2);                       \
      ps += __shfl_xor(ps, 4); ps += __shfl_xor(ps, 8);                       \
      if (ps > mx + 8.f) {                                                    \
        float rr = __expf(mx - ps);     /* first edge: exp(-huge) = 0 */      \
        den *= rr; u0 *= rr; u1 *= rr; mx = ps;                               \
      }                                                                       \
      float w = __expf(ps - mx);        /* bounded by e^8 */                  \
      den += w; u0 += w * v0; u1 += w * v1;                                   \
      int jr = je + 4;                                                        \
      if (jr < cnt) {                                                         \
        const f32x4* efp = (const f32x4*)(efeat + (size_t)i##S.x * 128) + cl * 2; \
        f##S##0 = __builtin_nontemporal_load(efp);                            \
        f##S##1 = __builtin_nontemporal_load(efp + 1);                        \
        const f32x4* hp = (const f32x4*)(h + (size_t)i##S.y * 128) + cl * 2;  \
        h##S##0 = hp[0]; h##S##1 = hp[1];                                     \
        if (je + 8 < cnt) i##S = epair[s0 + je + 8];                          \
      }                                                                       \
    }                                                                         \
  }
  for (int j = 0; j < jm; j += 4) {
    PROC(A, 0) PROC(B, 1) PROC(C, 2) PROC(D, 3)
  }
  #undef PROC

  if (valid) {
    if (cnt == 0) {
      *(f32x4*)&U[nb]     = (f32x4){0.f, 0.f, 0.f, 0.f};
      *(f32x4*)&U[nb + 4] = (f32x4){0.f, 0.f, 0.f, 0.f};
    } else {
      float inv = 1.f / den;             // den >= 1 (max term present)
      *(f32x4*)&U[nb]     = u0 * inv;
      *(f32x4*)&U[nb + 4] = u1 * inv;
    }
  }
}

// ---------------------------------------------------------------------------
// Final node GEMM: out = leaky(y2 + b1 + U@W1), deg==0 -> leaky(y3).
// ---------------------------------------------------------------------------
__global__ __launch_bounds__(256)
void gemm_fin(const float* __restrict__ A,       // U
              const u16* __restrict__ wf,        // W1 frags
              const float* __restrict__ biases,  // b1 at [0..127]
              const float* __restrict__ y2, const float* __restrict__ y3,
              const int* __restrict__ off, float* __restrict__ C, int M) {
  __shared__ u16 ah[64 * 136];
  __shared__ u16 al[64 * 136];
  const int tid = threadIdx.x;
  const long long rowBase = (long long)blockIdx.x * 64;
  #pragma unroll
  for (int it = 0; it < 8; ++it) {
    int idx = it * 256 + tid;
    int row = idx >> 5, c4 = idx & 31;
    long long gr = rowBase + row;
    float4 v = make_float4(0.f, 0.f, 0.f, 0.f);
    if (gr < M) v = ((const float4*)A)[gr * 32 + c4];
    u16 hb[4] = {f2bf(v.x), f2bf(v.y), f2bf(v.z), f2bf(v.w)};
    u16 lb[4] = {f2bf(v.x - bf2f(hb[0])), f2bf(v.y - bf2f(hb[1])),
                 f2bf(v.z - bf2f(hb[2])), f2bf(v.w - bf2f(hb[3]))};
    *(uint2*)&ah[row * 136 + c4 * 4] = *(uint2*)hb;
    *(uint2*)&al[row * 136 + c4 * 4] = *(uint2*)lb;
  }
  __syncthreads();
  const int wid = tid >> 6, lane = tid & 63, lrow = lane & 15, lk = lane >> 4;
  bf16x8 af[4], alf[4];
  #pragma unroll
  for (int kc = 0; kc < 4; ++kc) {
    af[kc]  = *(const bf16x8*)&ah[(wid * 16 + lrow) * 136 + kc * 32 + lk * 8];
    alf[kc] = *(const bf16x8*)&al[(wid * 16 + lrow) * 136 + kc * 32 + lk * 8];
  }
  f32x4 acc[8];
  #pragma unroll
  for (int t = 0; t < 8; ++t) acc[t] = (f32x4){0.f, 0.f, 0.f, 0.f};
  #pragma unroll
  for (int t = 0; t < 8; ++t) {
    #pragma unroll
    for (int kc = 0; kc < 4; ++kc) {
      bf16x8 bh = *(const bf16x8*)&wf[((t * 4 + kc) * 2) * 512 + lane * 8];
      bf16x8 bl = *(const bf16x8*)&wf[((t * 4 + kc) * 2 + 1) * 512 + lane * 8];
      acc[t] = __builtin_amdgcn_mfma_f32_16x16x32_bf16(af[kc],  bh, acc[t], 0, 0, 0);
      acc[t] = __builtin_amdgcn_mfma_f32_16x16x32_bf16(alf[kc], bh, acc[t], 0, 0, 0);
      acc[t] = __builtin_amdgcn_mfma_f32_16x16x32_bf16(af[kc],  bl, acc[t], 0, 0, 0);
    }
  }
  #pragma unroll
  for (int r = 0; r < 4; ++r) {
    long long row = rowBase + wid * 16 + lk * 4 + r;
    if (row >= M) continue;
    int dg = off[row + 1] - off[row];
    #pragma unroll
    for (int t = 0; t < 8; ++t) {
      int col = t * 16 + lrow;
      size_t o = (size_t)row * 128 + col;
      float v;
      if (dg) v = acc[t][r] + y2[o] + biases[col];
      else    v = y3[o];
      v = v >= 0.f ? v : v * NEG_SLOPE;
      C[o] = v;
    }
  }
}

extern "C" void kernel_launch(void* const* d_in, const int* in_sizes, int n_in,
                              void* d_out, int out_size, void* d_ws, size_t ws_size,
                              hipStream_t stream) {
  const int D = 128;
  const int N = in_sizes[0] / D;
  const int E = in_sizes[1] / D;

  const float* node  = (const float*)d_in[0];
  const float* edgef = (const float*)d_in[1];
  const int* src = (const int*)d_in[2];
  const int* dst = (const int*)d_in[3];

  // workspace carve (~134 MB)
  char* p = (char*)d_ws;
  u16*   wfrag = (u16*)p;   p += (size_t)8 * 32768 * 2;
  float* biasf = (float*)p; p += 4096;
  float* hT1   = (float*)p; p += (size_t)N * 512;
  float* y2    = (float*)p; p += (size_t)N * 512;
  float* y3    = (float*)p; p += (size_t)N * 512;
  float* h1    = (float*)p; p += (size_t)N * 512;
  float* Ub    = (float*)p; p += (size_t)N * 512;
  int* deg     = (int*)p;   p += (size_t)N * 4;
  int* off     = (int*)p;   p += (size_t)(N + 256) * 4;
  int* cursor  = (int*)p;   p += (size_t)N * 4;
  int* bsum    = (int*)p;   p += 1024;
  int2* epair  = (int2*)p;  p += (size_t)E * 8;
  (void)ws_size;

  prep_weights<<<64, 256, 0, stream>>>(
      (const float*)d_in[4],  (const float*)d_in[6],  (const float*)d_in[8],
      (const float*)d_in[10], (const float*)d_in[12], (const float*)d_in[14],
      (const float*)d_in[5],  (const float*)d_in[7],  (const float*)d_in[9],
      (const float*)d_in[11], (const float*)d_in[13], (const float*)d_in[15],
      wfrag, biasf);

  const int gN = (N + 63) / 64;
  const int eB = (E + 255) / 256;
  const int nb = (N + 1023) / 1024;

  hipMemsetAsync(deg, 0, (size_t)N * 4, stream);
  hist_k<<<eB, 256, 0, stream>>>(dst, deg, E);
  scan1<<<nb, 256, 0, stream>>>(deg, off, bsum, N);
  scan2<<<1, 256, 0, stream>>>(bsum, nb);
  scan3<<<(N + 256) / 256, 256, 0, stream>>>(off, bsum, cursor, N, E);
  scatter_k<<<eB, 256, 0, stream>>>(dst, src, cursor, epair, E);

  for (int l = 0; l < 2; ++l) {
    const float* h = (l == 0) ? node : h1;
    float* hout = (l == 0) ? h1 : (float*)d_out;
    const u16* wf1 = wfrag + (size_t)(l * 3 + 0) * 32768;
    const u16* wf2 = wfrag + (size_t)(l * 3 + 1) * 32768;
    const u16* wf3 = wfrag + (size_t)(l * 3 + 2) * 32768;
    const u16* wfT = wfrag + (size_t)(6 + l) * 32768;
    const float* bset = biasf + l * 384;   // [b1|b2|b3] for this layer

    gemm_n3t<<<gN, 256, 0, stream>>>(h, wfT, wf2, wf3, bset, off, hT1, y2, y3, N);
    edge_agg<<<(N + 15) / 16, 256, 0, stream>>>(edgef, h, hT1, off, epair, Ub, N);
    gemm_fin<<<gN, 256, 0, stream>>>(Ub, wf1, bset, y2, y3, off, hout, N);
  }
}